// Round 4
// baseline (269.351 us; speedup 1.0000x reference)
//
#include <hip/hip_runtime.h>
#include <stdint.h>

#define HIDDEN 1024
#define BATCH  4
#define SEQ    2048
#define TOKENS (BATCH * SEQ)      // 8192
#define QKVD   (3 * HIDDEN)       // 3072

typedef unsigned short u16;
typedef __attribute__((ext_vector_type(8))) short   short8;   // 8 bf16 = 4 VGPRs
typedef __attribute__((ext_vector_type(4))) float   floatx4;

// deterministic round-to-nearest-even f32 -> bf16 (no NaN inputs here)
__device__ __forceinline__ u16 f32_bf16_rne(float f) {
    unsigned int u = __float_as_uint(f);
    u += 0x7FFFu + ((u >> 16) & 1u);
    return (u16)(u >> 16);
}

// async global->LDS, 16B per lane. LDS dest is wave-uniform base + lane*16.
__device__ __forceinline__ void gl16(const u16* g, u16* l) {
    __builtin_amdgcn_global_load_lds(
        (const __attribute__((address_space(1))) void*)g,
        (__attribute__((address_space(3))) void*)l, 16, 0, 0);
}

// window barrier: sched_barrier(0) pins MFMA/read motion (a "memory" clobber
// alone does not order register-only MFMAs - rule #18), then raw s_barrier.
// NO lgkmcnt here: pending ds_reads (the read-ahead batch) stay in flight
// across the barrier; the compiler inserts precise counted lgkmcnt waits in
// front of each MFMA cluster based on register dependences.
#define PBAR() do { __builtin_amdgcn_sched_barrier(0); \
    asm volatile("s_barrier" ::: "memory"); } while (0)
// counted vmcnt: leave the 4 newest staging loads in flight (NEVER 0 in-loop)
#define VM4() do { __builtin_amdgcn_sched_barrier(0); \
    asm volatile("s_waitcnt vmcnt(4)" ::: "memory"); } while (0)

// ---------------------------------------------------------------- convert
__global__ __launch_bounds__(256) void cvt2_bf16_kernel(
        const float* __restrict__ sa, const float* __restrict__ sb,
        u16* __restrict__ da, u16* __restrict__ db, int n4a, int n4tot) {
    int i = blockIdx.x * 256 + threadIdx.x;
    if (i >= n4tot) return;
    float4 v;
    if (i < n4a) v = ((const float4*)sa)[i];
    else         v = ((const float4*)sb)[i - n4a];
    ushort4 o;
    o.x = f32_bf16_rne(v.x); o.y = f32_bf16_rne(v.y);
    o.z = f32_bf16_rne(v.z); o.w = f32_bf16_rne(v.w);
    if (i < n4a) ((ushort4*)da)[i] = o;
    else         ((ushort4*)db)[i - n4a] = o;
}

// ---------------------------------------------------------------- GEMM (NT)
// C[M,N] = A[M,K]*B[N,K]^T.  BM=128, BN=256, BK=64. 512 threads = 8 waves
// (2M x 4N), per-wave 64x64 = 4x4 grid of 16x16x32 bf16 MFMA.
//
// Round 9: READ-AHEAD register pipeline. Rounds 6-8 all alternated
// [ds_read window | barrier | MFMA window] -> LDS and matrix pipes serialize
// (per-block util pinned ~48%). Here window C_i issues the ds_reads feeding
// C_{i+1}'s MFMAs, so LDS drains UNDER the MFMA clusters and the compiler's
// dependence-derived counted lgkmcnt (never 0) implements the overlap.
// 4 windows per K-tile T (buf q = T&1, other buf p holds T+1):
//   C0: rd bHi(T)            | MFMA aF0·bLo (acc[0..1][0..1]) | PBAR
//   C1: rd aF1(T)            | MFMA aF0·bHi (acc[0..1][2..3]) | PBAR
//   C2: stage B(T+2)->q      | MFMA aF1·bHi (acc[2..3][2..3]) | VM4 PBAR
//   C3: rd aF0',bLo'(T+1 <-p); stage A(T+2)->q
//                            | MFMA aF1·bLo (acc[2..3][0..1]) | PBAR
// aF0/bLo are double-banked (cross-K-tile lifetime); aF1/bHi single.
// Race-safety (skew bounded <1 window by the per-window barrier):
//  - STB(C2) overwrites q's B-region: all B reads of tile T drained before
//    each wave's C1 cluster (compiler wait), and C2 entry requires the
//    C1-end barrier -> drained for ALL waves.  STA(C3) likewise (A reads
//    drained before C2 cluster; C3 entry requires C2-end barrier).
//  - C3's reads of buf p (tile T+1): T+1's 6 loads were issued in GROUP(T-1)
//    C2/C3; at C2(T)-end the FIFO is [6 of T+1][4 B of T+2] -> vmcnt(4)
//    drains T+1, barrier publishes to all waves, THEN C3 reads.  Invariant:
//    exactly 6 loads (next tile) in flight across every GROUP boundary.
//
// Slab layout (verified rounds 3-8, 0 bank conflicts): row = 64 B, 16B slot
// XOR-swizzled phys = slot ^ ((row>>1)&3); staged linearly by global_load_lds
// with the inverse swizzle applied to the GLOBAL source address.
//
// Grids: QKV 12x64=768 (3.0 CU-rounds), scores 8x16x4=512 (2.0),
// PV 4x16x4=256 (1.0) - no partial-round tail anywhere.
//
// EPI: 0 = bf16 store + bias[col]; 1 = f32 store * scale; 2 = f32 store.
template <int EPI>
__global__ __launch_bounds__(512, 2) void gemm_bt(
        const u16* __restrict__ A, const u16* __restrict__ B,
        void* __restrict__ Cv, const float* __restrict__ bias,
        int K, int lda, int ldb, int ldc,
        size_t sA, size_t sB, size_t sC, float scale) {
    constexpr int ASLAB = 128 * 64;                 // 8 KB per A k-slab
    constexpr int BSLAB = 256 * 64;                 // 16 KB per B k-slab
    constexpr int BUFB  = 2 * ASLAB + 2 * BSLAB;    // 48 KB per buffer
    __shared__ __align__(16) char lds[2][BUFB];     // 96 KB

    const int t    = threadIdx.x;
    const int lane = t & 63;
    const int wid  = t >> 6;             // 0..7
    const int wr   = wid >> 2;           // 0..1  (M half, 64 rows)
    const int wc   = wid & 3;            // 0..3  (N quarter, 64 cols)
    const int bm   = blockIdx.y * 128;
    const int bn   = blockIdx.x * 256;

    const u16* Ab = A + (size_t)blockIdx.z * sA;
    const u16* Bb = B + (size_t)blockIdx.z * sB;

    // staging source: thread t -> row t>>2 (+128 for B's 2nd half), phys slot
    // t&3, global slot = (t&3) ^ ((row>>1)&3)  (same swizzle for row+128)
    const int r0 = t >> 2;
    const int sl = (t & 3) ^ ((r0 >> 1) & 3);
    const u16* gA0 = Ab + (size_t)(bm + r0) * lda + sl * 8;
    const u16* gB0 = Bb + (size_t)(bn + r0) * ldb + sl * 8;
    const u16* gB1 = gB0 + (size_t)128 * ldb;

    // fragment read geometry (verified 16x16x32 mappings)
    const int fr  = lane & 15;
    const int kc  = lane >> 4;
    const int frb = fr * 64 + ((kc ^ ((fr >> 1) & 3)) << 4);

    floatx4 acc[4][4];
#pragma unroll
    for (int i = 0; i < 4; i++)
#pragma unroll
        for (int j = 0; j < 4; j++) acc[i][j] = (floatx4){0.f, 0.f, 0.f, 0.f};

    short8 aF0A[2][2], aF0B[2][2];   // banked A frags, mi 0..1
    short8 bLoA[2][2], bLoB[2][2];   // banked B frags, ni 0..1
    short8 aF1[2][2],  bHi[2][2];    // single-banked: mi 2..3 / ni 2..3

    auto rdA = [&](short8 (&dst)[2][2], const char* bp, int miBase) {
#pragma unroll
        for (int m = 0; m < 2; m++)
#pragma unroll
            for (int ks = 0; ks < 2; ks++)
                dst[m][ks] = *(const short8*)(bp + ks * ASLAB +
                    (wr * 64 + (miBase + m) * 16) * 64 + frb);
    };
    auto rdB = [&](short8 (&dst)[2][2], const char* bp, int niBase) {
#pragma unroll
        for (int n = 0; n < 2; n++)
#pragma unroll
            for (int ks = 0; ks < 2; ks++)
                dst[n][ks] = *(const short8*)(bp + 2 * ASLAB + ks * BSLAB +
                    (wc * 64 + (niBase + n) * 16) * 64 + frb);
    };
    auto mf8 = [&](short8 (&av)[2][2], short8 (&bv)[2][2], int miB, int niB) {
        __builtin_amdgcn_s_setprio(1);
#pragma unroll
        for (int m = 0; m < 2; m++)
#pragma unroll
            for (int n = 0; n < 2; n++)
#pragma unroll
                for (int ks = 0; ks < 2; ks++)
                    acc[miB + m][niB + n] = __builtin_amdgcn_mfma_f32_16x16x32_bf16(
                        av[m][ks], bv[n][ks], acc[miB + m][niB + n], 0, 0, 0);
        __builtin_amdgcn_s_setprio(0);
    };

#define STA(bq, sc) do { \
    char* d = &lds[bq][0] + wid * 1024; \
    gl16(gA0 + (sc),      (u16*)d); \
    gl16(gA0 + (sc) + 32, (u16*)(d + ASLAB)); \
  } while (0)
#define STB(bq, sc) do { \
    char* d = &lds[bq][2 * ASLAB] + wid * 1024; \
    gl16(gB0 + (sc),      (u16*)d); \
    gl16(gB1 + (sc),      (u16*)(d + 8192)); \
    gl16(gB0 + (sc) + 32, (u16*)(d + BSLAB)); \
    gl16(gB1 + (sc) + 32, (u16*)(d + BSLAB + 8192)); \
  } while (0)

#define GROUP(q, AF0C, BLOC, AF0N, BLON, SCN) { \
    const char* bp = lds[q]; \
    const char* np = lds[q ^ 1]; \
    rdB(bHi, bp, 2); \
    mf8(AF0C, BLOC, 0, 0); PBAR(); \
    rdA(aF1, bp, 2); \
    mf8(AF0C, bHi, 0, 2); PBAR(); \
    STB(q, SCN); \
    mf8(aF1, bHi, 2, 2); VM4(); PBAR(); \
    rdA(AF0N, np, 0); rdB(BLON, np, 0); STA(q, SCN); \
    mf8(aF1, BLOC, 2, 0); PBAR(); \
}

    // prologue: stage tile0 -> buf0 (6 loads), tile1 -> buf1 (6 loads);
    // vmcnt(6) drains tile0, leaves tile1's 6 in flight (= loop invariant);
    // then pre-read tile0's aF0/bLo (the C3(-1) job).
    STA(0, 0); STB(0, 0);
    STA(1, 64); STB(1, 64);
    __builtin_amdgcn_sched_barrier(0);
    asm volatile("s_waitcnt vmcnt(6)" ::: "memory");
    PBAR();
    rdA(aF0A, lds[0], 0); rdB(bLoA, lds[0], 0);

    const int nk = K >> 6;               // 64-wide K-tiles (16 or 32), even
    for (int T = 0; T < nk; T += 2) {
        const int sc2 = (T + 2 < nk ? T + 2 : nk - 1) << 6;   // tail clamp:
        const int sc3 = (T + 3 < nk ? T + 3 : nk - 1) << 6;   // harmless restage
        GROUP(0, aF0A, bLoA, aF0B, bLoB, sc2)
        GROUP(1, aF0B, bLoB, aF0A, bLoA, sc3)
    }
    asm volatile("s_waitcnt vmcnt(0)" ::: "memory");   // drain tail restages

#undef GROUP
#undef STB
#undef STA

    // epilogue: C/D 16x16 mapping col=lane&15, row=(lane>>4)*4+reg
    const int crow0 = bm + wr * 64 + kc * 4;
    const int ccol0 = bn + wc * 64 + fr;
    const size_t coff = (size_t)blockIdx.z * sC;

    if (EPI == 0) {
        u16* C = (u16*)Cv;
        float bv[4];
#pragma unroll
        for (int ni = 0; ni < 4; ni++) bv[ni] = bias[ccol0 + ni * 16];
#pragma unroll
        for (int mi = 0; mi < 4; mi++)
#pragma unroll
            for (int ni = 0; ni < 4; ni++)
#pragma unroll
                for (int r = 0; r < 4; r++)
                    C[coff + (size_t)(crow0 + mi * 16 + r) * ldc + (ccol0 + ni * 16)] =
                        f32_bf16_rne(acc[mi][ni][r] + bv[ni]);
    } else {
        float* C = (float*)Cv;
#pragma unroll
        for (int mi = 0; mi < 4; mi++)
#pragma unroll
            for (int ni = 0; ni < 4; ni++)
#pragma unroll
                for (int r = 0; r < 4; r++) {
                    float v = acc[mi][ni][r];
                    if (EPI == 1) v *= scale;
                    C[coff + (size_t)(crow0 + mi * 16 + r) * ldc + (ccol0 + ni * 16)] = v;
                }
    }
}

// ---------------------------------------------------------------- softmax
// one block per row; 2048 fp32 scores (already scaled) -> 2048 bf16 probs
__global__ __launch_bounds__(256) void softmax_kernel(
        const float* __restrict__ S, u16* __restrict__ P) {
    __shared__ float redm[4];
    __shared__ float reds[4];
    const size_t base = (size_t)blockIdx.x * SEQ;
    const int t = threadIdx.x, lane = t & 63, wid = t >> 6;
    const float4* src = (const float4*)(S + base);
    float4 a = src[t], b = src[t + 256];

    float m = fmaxf(fmaxf(fmaxf(a.x, a.y), fmaxf(a.z, a.w)),
                    fmaxf(fmaxf(b.x, b.y), fmaxf(b.z, b.w)));
#pragma unroll
    for (int off = 32; off; off >>= 1) m = fmaxf(m, __shfl_xor(m, off, 64));
    if (lane == 0) redm[wid] = m;
    __syncthreads();
    m = fmaxf(fmaxf(redm[0], redm[1]), fmaxf(redm[2], redm[3]));

    float e[8];
    e[0] = __expf(a.x - m); e[1] = __expf(a.y - m);
    e[2] = __expf(a.z - m); e[3] = __expf(a.w - m);
    e[4] = __expf(b.x - m); e[5] = __expf(b.y - m);
    e[6] = __expf(b.z - m); e[7] = __expf(b.w - m);
    float s = e[0] + e[1] + e[2] + e[3] + e[4] + e[5] + e[6] + e[7];
#pragma unroll
    for (int off = 32; off; off >>= 1) s += __shfl_xor(s, off, 64);
    if (lane == 0) reds[wid] = s;
    __syncthreads();
    s = reds[0] + reds[1] + reds[2] + reds[3];
    const float r = 1.f / s;

    ushort4* dst = (ushort4*)(P + base);
    ushort4 o0, o1;
    o0.x = f32_bf16_rne(e[0] * r); o0.y = f32_bf16_rne(e[1] * r);
    o0.z = f32_bf16_rne(e[2] * r); o0.w = f32_bf16_rne(e[3] * r);
    o1.x = f32_bf16_rne(e[4] * r); o1.y = f32_bf16_rne(e[5] * r);
    o1.z = f32_bf16_rne(e[6] * r); o1.w = f32_bf16_rne(e[7] * r);
    dst[t] = o0;
    dst[t + 256] = o1;
}

// ---------------------------------------------------------------- V transpose
// Vt[b][h][s] <- qkv[b*SEQ+s][2*HIDDEN+h], 64x64 LDS tiles, pad 66 (bank-safe)
__global__ __launch_bounds__(256) void transposeV_kernel(
        const u16* __restrict__ qkv, u16* __restrict__ Vt) {
    __shared__ u16 tile[64][66];
    const int b = blockIdx.z;
    const int s0 = blockIdx.x * 64, h0 = blockIdx.y * 64;
    const int t = threadIdx.x;
    const int c = t & 63, r4 = t >> 6;
#pragma unroll
    for (int i = 0; i < 16; i++) {
        int sl = i * 4 + r4;
        tile[sl][c] = qkv[(size_t)(b * SEQ + s0 + sl) * QKVD + 2 * HIDDEN + h0 + c];
    }
    __syncthreads();
#pragma unroll
    for (int i = 0; i < 16; i++) {
        int hl = i * 4 + r4;
        Vt[(size_t)(b * HIDDEN + h0 + hl) * SEQ + s0 + c] = tile[c][hl];
    }
}

// ---------------------------------------------------------------- launch
extern "C" void kernel_launch(void* const* d_in, const int* in_sizes, int n_in,
                              void* d_out, int out_size, void* d_ws, size_t ws_size,
                              hipStream_t stream) {
    const float* x    = (const float*)d_in[0];   // [4,2048,1024]
    const float* W    = (const float*)d_in[1];   // [3072,1024]
    const float* bias = (const float*)d_in[2];   // [3072]
    float* out = (float*)d_out;                  // [4,2048,1024]

    // workspace layout (191 MB total)
    u16* Xb  = (u16*)d_ws;                                  // 8192x1024 bf16
    u16* Wb  = Xb + (size_t)TOKENS * HIDDEN;                // 3072x1024 bf16
    u16* qkv = Wb + (size_t)QKVD * HIDDEN;                  // 8192x3072 bf16
    float* scores = (float*)(qkv + (size_t)TOKENS * QKVD);  // 4x2048x2048 f32
    u16* P  = (u16*)(scores + (size_t)BATCH * SEQ * SEQ);   // 4x2048x2048 bf16
    u16* Vt = P + (size_t)BATCH * SEQ * SEQ;                // 4x1024x2048 bf16

    // 1) fp32 -> bf16 casts (both tensors, one launch)
    {
        const int n4a = TOKENS * HIDDEN / 4;
        const int n4b = QKVD * HIDDEN / 4;
        const int n4t = n4a + n4b;
        cvt2_bf16_kernel<<<(n4t + 255) / 256, 256, 0, stream>>>(x, W, Xb, Wb, n4a, n4t);
    }

    // 2) QKV projection: qkv = Xb @ Wb^T + bias (bf16 out)  grid 12x64 = 768
    gemm_bt<0><<<dim3(QKVD / 256, TOKENS / 128, 1), 512, 0, stream>>>(
        Xb, Wb, qkv, bias, HIDDEN, HIDDEN, HIDDEN, QKVD, 0, 0, 0, 1.f);

    // 3) scores = scale * Q @ K^T per batch (f32 out)  grid 8x16x4 = 512
    gemm_bt<1><<<dim3(SEQ / 256, SEQ / 128, BATCH), 512, 0, stream>>>(
        qkv, qkv + HIDDEN, scores, nullptr, HIDDEN, QKVD, QKVD, SEQ,
        (size_t)SEQ * QKVD, (size_t)SEQ * QKVD, (size_t)SEQ * SEQ, 0.03125f);

    // 4) row softmax -> bf16 P
    softmax_kernel<<<BATCH * SEQ, 256, 0, stream>>>(scores, P);

    // 5) V transpose (bias already folded in step 2)
    transposeV_kernel<<<dim3(SEQ / 64, HIDDEN / 64, BATCH), 256, 0, stream>>>(qkv, Vt);

    // 6) out = P @ Vt^T per batch (f32 out)  grid 4x16x4 = 256
    gemm_bt<2><<<dim3(HIDDEN / 256, SEQ / 128, BATCH), 512, 0, stream>>>(
        P, Vt, out, nullptr, SEQ, SEQ, SEQ, HIDDEN,
        (size_t)SEQ * SEQ, (size_t)HIDDEN * SEQ, (size_t)SEQ * HIDDEN, 1.f);
}

// Round 5
// 259.323 us; speedup vs baseline: 1.0387x; 1.0387x over previous
//
#include <hip/hip_runtime.h>
#include <stdint.h>

#define HIDDEN 1024
#define BATCH  4
#define SEQ    2048
#define TOKENS (BATCH * SEQ)      // 8192
#define QKVD   (3 * HIDDEN)       // 3072

typedef unsigned short u16;
typedef __attribute__((ext_vector_type(8))) short   short8;   // 8 bf16 = 4 VGPRs
typedef __attribute__((ext_vector_type(8))) unsigned short ushort8;
typedef __attribute__((ext_vector_type(4))) float   floatx4;

// deterministic round-to-nearest-even f32 -> bf16 (no NaN inputs here)
__device__ __forceinline__ u16 f32_bf16_rne(float f) {
    unsigned int u = __float_as_uint(f);
    u += 0x7FFFu + ((u >> 16) & 1u);
    return (u16)(u >> 16);
}

// async global->LDS, 16B per lane. LDS dest is wave-uniform base + lane*16.
__device__ __forceinline__ void gl16(const u16* g, u16* l) {
    __builtin_amdgcn_global_load_lds(
        (const __attribute__((address_space(1))) void*)g,
        (__attribute__((address_space(3))) void*)l, 16, 0, 0);
}

// ---- sync macros (two flavors, each verbatim from its measured-best round)
// R1 4-phase: wait until only the newest 3 staging loads remain in flight.
#define SYNC3() do { __builtin_amdgcn_sched_barrier(0); \
    asm volatile("s_waitcnt vmcnt(3)\n\ts_barrier" ::: "memory"); } while (0)
// R3 8-phase: raw barrier / lgkm drain / counted vmcnt(4)
#define PBAR() do { __builtin_amdgcn_sched_barrier(0); \
    asm volatile("s_barrier" ::: "memory"); } while (0)
#define LG0() asm volatile("s_waitcnt lgkmcnt(0)" ::: "memory")
#define VM4() do { __builtin_amdgcn_sched_barrier(0); \
    asm volatile("s_waitcnt vmcnt(4)" ::: "memory"); } while (0)

// ---------------------------------------------------------------- convert
__global__ __launch_bounds__(256) void cvt2_bf16_kernel(
        const float* __restrict__ sa, const float* __restrict__ sb,
        u16* __restrict__ da, u16* __restrict__ db, int n4a, int n4tot) {
    int i = blockIdx.x * 256 + threadIdx.x;
    if (i >= n4tot) return;
    float4 v;
    if (i < n4a) v = ((const float4*)sa)[i];
    else         v = ((const float4*)sb)[i - n4a];
    ushort4 o;
    o.x = f32_bf16_rne(v.x); o.y = f32_bf16_rne(v.y);
    o.z = f32_bf16_rne(v.z); o.w = f32_bf16_rne(v.w);
    if (i < n4a) ((ushort4*)da)[i] = o;
    else         ((ushort4*)db)[i - n4a] = o;
}

// ---------------------------------------------------------------- QKV GEMM
// qkv = Xb @ Wb^T + bias, with FUSED V-transpose.  This is the round-1
// 4-phase kernel (measured best QKV: 65.0 us vs 67.0/78.5/69.4/69.3 for the
// other four structures) with a split epilogue:
//   blockIdx.x < 8  : bf16+bias store to qkv (Q,K columns)
//   blockIdx.x >= 8 : V columns -> bias, LDS transpose bounce, write Vt
//                     directly (skips the dead qkv V-write; replaces the
//                     separate transposeV kernel: -33.6 MB traffic -launch)
// BM=128, BN=256, BK=64, 512 threads, per-wave 64x64.  Slab layout + XOR
// swizzle + vmcnt(3) pipeline verbatim from round 1 (passed, 0 conflicts).
__global__ __launch_bounds__(512, 2) void gemm_qkv(
        const u16* __restrict__ A, const u16* __restrict__ B,
        u16* __restrict__ C, u16* __restrict__ Vt,
        const float* __restrict__ bias) {
    __shared__ __align__(16) u16 lds[2][2][(128 + 256) * 32];   // 96 KB

    const int t    = threadIdx.x;
    const int lane = t & 63;
    const int wid  = t >> 6;
    const int wr   = wid >> 2;           // 0..1
    const int wc   = wid & 3;            // 0..3
    const int bm   = blockIdx.y * 128;
    const int bn   = blockIdx.x * 256;

    // staging source: thread t -> row t>>2, phys slot t&3,
    // global slot = (t&3) ^ ((row>>1)&3)
    const int rA  = t >> 2;
    const int sl  = (t & 3) ^ ((rA >> 1) & 3);
    const u16* gA  = A + (size_t)(bm + rA) * 1024 + sl * 8;
    const u16* gB0 = B + (size_t)(bn + rA) * 1024 + sl * 8;
    const u16* gB1 = gB0 + (size_t)128 * 1024;

    // fragment read geometry (verified 16x16x32 mappings)
    const int fr = lane & 15;
    const int kc = lane >> 4;
    const int fo = ((kc ^ ((fr >> 1) & 3)) << 4);
    const int aoffB = (wr * 64 + fr) * 64 + fo;
    const int boffB = (wc * 64 + fr) * 64 + fo;

    floatx4 acc[4][4];
#pragma unroll
    for (int i = 0; i < 4; i++)
#pragma unroll
        for (int j = 0; j < 4; j++) acc[i][j] = (floatx4){0.f, 0.f, 0.f, 0.f};

    short8 bfr0, bfr1, bfr2, bfr3, va0, va1;

#define LDB4(BASE) \
    bfr0 = *(const short8*)((BASE) + boffB);        \
    bfr1 = *(const short8*)((BASE) + boffB + 1024); \
    bfr2 = *(const short8*)((BASE) + boffB + 2048); \
    bfr3 = *(const short8*)((BASE) + boffB + 3072);

#define MFMA2(MI, A0, A1) \
    __builtin_amdgcn_s_setprio(1); \
    acc[MI][0]     = __builtin_amdgcn_mfma_f32_16x16x32_bf16(A0, bfr0, acc[MI][0], 0, 0, 0); \
    acc[MI][1]     = __builtin_amdgcn_mfma_f32_16x16x32_bf16(A0, bfr1, acc[MI][1], 0, 0, 0); \
    acc[MI][2]     = __builtin_amdgcn_mfma_f32_16x16x32_bf16(A0, bfr2, acc[MI][2], 0, 0, 0); \
    acc[MI][3]     = __builtin_amdgcn_mfma_f32_16x16x32_bf16(A0, bfr3, acc[MI][3], 0, 0, 0); \
    acc[(MI)+1][0] = __builtin_amdgcn_mfma_f32_16x16x32_bf16(A1, bfr0, acc[(MI)+1][0], 0, 0, 0); \
    acc[(MI)+1][1] = __builtin_amdgcn_mfma_f32_16x16x32_bf16(A1, bfr1, acc[(MI)+1][1], 0, 0, 0); \
    acc[(MI)+1][2] = __builtin_amdgcn_mfma_f32_16x16x32_bf16(A1, bfr2, acc[(MI)+1][2], 0, 0, 0); \
    acc[(MI)+1][3] = __builtin_amdgcn_mfma_f32_16x16x32_bf16(A1, bfr3, acc[(MI)+1][3], 0, 0, 0); \
    __builtin_amdgcn_s_setprio(0);

#define ITER(BUF, SBUF, SCOL) { \
    const char* As0_ = (const char*)&lds[BUF][0][0]; \
    const char* Bs0_ = As0_ + 8192; \
    const char* As1_ = (const char*)&lds[BUF][1][0]; \
    const char* Bs1_ = As1_ + 8192; \
    gl16(gA + (SCOL),       (u16*)((char*)&lds[SBUF][0][0]    + wid * 1024)); \
    LDB4(Bs0_); \
    va0 = *(const short8*)(As0_ + aoffB); \
    va1 = *(const short8*)(As0_ + aoffB + 1024); \
    MFMA2(0, va0, va1); \
    gl16(gB0 + (SCOL),      (u16*)((char*)&lds[SBUF][0][4096] + wid * 1024)); \
    gl16(gB1 + (SCOL),      (u16*)((char*)&lds[SBUF][0][8192] + wid * 1024)); \
    va0 = *(const short8*)(As0_ + aoffB + 2048); \
    va1 = *(const short8*)(As0_ + aoffB + 3072); \
    MFMA2(2, va0, va1); \
    SYNC3(); \
    gl16(gA + (SCOL) + 32,  (u16*)((char*)&lds[SBUF][1][0]    + wid * 1024)); \
    LDB4(Bs1_); \
    va0 = *(const short8*)(As1_ + aoffB); \
    va1 = *(const short8*)(As1_ + aoffB + 1024); \
    MFMA2(0, va0, va1); \
    gl16(gB0 + (SCOL) + 32, (u16*)((char*)&lds[SBUF][1][4096] + wid * 1024)); \
    gl16(gB1 + (SCOL) + 32, (u16*)((char*)&lds[SBUF][1][8192] + wid * 1024)); \
    va0 = *(const short8*)(As1_ + aoffB + 2048); \
    va1 = *(const short8*)(As1_ + aoffB + 3072); \
    MFMA2(2, va0, va1); \
    SYNC3(); }

    // prologue: tile 0 -> buf0 (ks0 set, ks1 set); vmcnt(3) drains the ks0
    // set, leaves the ks1 set in flight (= steady state).
    gl16(gA,       (u16*)((char*)&lds[0][0][0]    + wid * 1024));
    gl16(gB0,      (u16*)((char*)&lds[0][0][4096] + wid * 1024));
    gl16(gB1,      (u16*)((char*)&lds[0][0][8192] + wid * 1024));
    gl16(gA + 32,  (u16*)((char*)&lds[0][1][0]    + wid * 1024));
    gl16(gB0 + 32, (u16*)((char*)&lds[0][1][4096] + wid * 1024));
    gl16(gB1 + 32, (u16*)((char*)&lds[0][1][8192] + wid * 1024));
    SYNC3();

    const int nk = 1024 >> 6;            // 16 K-tiles
    for (int kt = 0; kt < nk; kt += 2) {
        const int c1 = (kt + 1) << 6;
        const int c2 = (kt + 2 < nk ? (kt + 2) : (nk - 1)) << 6;
        ITER(0, 1, c1)
        ITER(1, 0, c2)
    }
    asm volatile("s_waitcnt vmcnt(0)" ::: "memory");

#undef ITER
#undef MFMA2
#undef LDB4

    // epilogue: C/D 16x16 mapping col=lane&15, row=(lane>>4)*4+reg
    const int crow0 = bm + wr * 64 + kc * 4;
    const int ccol0 = bn + wc * 64 + fr;
    float bv[4];
#pragma unroll
    for (int ni = 0; ni < 4; ni++) bv[ni] = bias[ccol0 + ni * 16];

    if (blockIdx.x < 8) {
        // Q,K columns: normal bf16 store to qkv
#pragma unroll
        for (int mi = 0; mi < 4; mi++)
#pragma unroll
            for (int ni = 0; ni < 4; ni++)
#pragma unroll
                for (int r = 0; r < 4; r++)
                    C[(size_t)(crow0 + mi * 16 + r) * QKVD + (ccol0 + ni * 16)] =
                        f32_bf16_rne(acc[mi][ni][r] + bv[ni]);
    } else {
        // V columns: transpose 128x256 tile through LDS, write Vt directly.
        // (nothing reads qkv's V columns once Vt exists -> skip that write)
        __syncthreads();                     // all K-loop LDS reads done
        u16 (*TB)[258] = (u16(*)[258]) & lds[0][0][0];   // 128x258 u16, 66 KB
        const int lr0 = wr * 64 + kc * 4;
        const int lc0 = wc * 64 + fr;
#pragma unroll
        for (int mi = 0; mi < 4; mi++)
#pragma unroll
            for (int ni = 0; ni < 4; ni++)
#pragma unroll
                for (int r = 0; r < 4; r++)
                    TB[lr0 + mi * 16 + r][lc0 + ni * 16] =
                        f32_bf16_rne(acc[mi][ni][r] + bv[ni]);
        __syncthreads();
        const int b  = bm >> 11;             // batch
        const int sb = bm & 2047;            // s base within batch
        const int h0 = bn - 2048;            // V feature base
        // 2 iterations x 512 threads cover 256 h x 4 s-chunks(32 each).
        // LDS column reads: consecutive lanes -> consecutive h -> 32 banks,
        // 2 lanes/dword (broadcast) = conflict-free.  Stores: 64 B/lane
        // contiguous along s (full cache lines).
        for (int it = 0; it < 2; ++it) {
            const int task = it * 512 + t;
            const int h    = task & 255;
            const int s0   = (task >> 8) * 32;
            ushort8 v[4];
#pragma unroll
            for (int j8 = 0; j8 < 4; ++j8)
#pragma unroll
                for (int j = 0; j < 8; ++j)
                    v[j8][j] = TB[s0 + j8 * 8 + j][h];
            u16* dst = Vt + (size_t)(b * 1024 + h0 + h) * 2048 + sb + s0;
#pragma unroll
            for (int j8 = 0; j8 < 4; ++j8)
                *(ushort8*)(dst + j8 * 8) = v[j8];
        }
    }
}

// ---------------------------------------------------------------- GEMM (NT)
// Round-3 8-phase template, verbatim (measured best for scores+PV: their
// pair ran ~14 us faster than the 4-phase pair, totals 258.2 vs 268.0).
// C[M,N] = A[M,K]*B[N,K]^T.  BM=2*WM, BN=256, BK=64, 512 threads, 8 waves.
// EPI: 1 = f32 store * scale; 2 = f32 store.
template <int EPI, int WM>
__global__ __launch_bounds__(512, 2) void gemm_bt(
        const u16* __restrict__ A, const u16* __restrict__ B,
        void* __restrict__ Cv, const float* __restrict__ bias,
        int K, int lda, int ldb, int ldc,
        size_t sA, size_t sB, size_t sC, float scale) {
    constexpr int BM    = 2 * WM;
    constexpr int MIH   = WM / 32;
    constexpr int ASLAB = BM * 64;
    constexpr int BSLAB = 256 * 64;
    constexpr int BUFB  = 2 * ASLAB + 2 * BSLAB;
    __shared__ __align__(16) char lds[2][BUFB];

    const int t    = threadIdx.x;
    const int lane = t & 63;
    const int wid  = t >> 6;
    const int wr   = wid >> 2;
    const int wc   = wid & 3;
    const int bm   = blockIdx.y * BM;
    const int bn   = blockIdx.x * 256;

    const u16* Ab = A + (size_t)blockIdx.z * sA;
    const u16* Bb = B + (size_t)blockIdx.z * sB;

    const int r0 = t >> 2;
    const int sl = (t & 3) ^ ((r0 >> 1) & 3);
    const u16* gA0 = Ab + (size_t)(bm + r0) * lda + sl * 8;
    const u16* gA1 = gA0 + (size_t)128 * lda;
    const u16* gB0 = Bb + (size_t)(bn + r0) * ldb + sl * 8;
    const u16* gB1 = gB0 + (size_t)128 * ldb;

    const int fr  = lane & 15;
    const int kc  = lane >> 4;
    const int frb = fr * 64 + ((kc ^ ((fr >> 1) & 3)) << 4);

    floatx4 acc[2 * MIH][4];
#pragma unroll
    for (int i = 0; i < 2 * MIH; i++)
#pragma unroll
        for (int j = 0; j < 4; j++) acc[i][j] = (floatx4){0.f, 0.f, 0.f, 0.f};

    short8 aF[MIH][2], bLo[2][2], bHi[2][2];

    auto rdA = [&](short8 (&dst)[MIH][2], const char* bp, int miBase) {
#pragma unroll
        for (int m = 0; m < MIH; m++)
#pragma unroll
            for (int ks = 0; ks < 2; ks++)
                dst[m][ks] = *(const short8*)(bp + ks * ASLAB +
                    (wr * WM + (miBase + m) * 16) * 64 + frb);
    };
    auto rdB = [&](short8 (&dst)[2][2], const char* bp, int niBase) {
#pragma unroll
        for (int n = 0; n < 2; n++)
#pragma unroll
            for (int ks = 0; ks < 2; ks++)
                dst[n][ks] = *(const short8*)(bp + 2 * ASLAB + ks * BSLAB +
                    (wc * 64 + (niBase + n) * 16) * 64 + frb);
    };
    auto mf = [&](short8 (&av)[MIH][2], short8 (&bv)[2][2], int miB, int niB) {
        __builtin_amdgcn_s_setprio(1);
#pragma unroll
        for (int m = 0; m < MIH; m++)
#pragma unroll
            for (int n = 0; n < 2; n++)
#pragma unroll
                for (int ks = 0; ks < 2; ks++)
                    acc[miB + m][niB + n] = __builtin_amdgcn_mfma_f32_16x16x32_bf16(
                        av[m][ks], bv[n][ks], acc[miB + m][niB + n], 0, 0, 0);
        __builtin_amdgcn_s_setprio(0);
    };

#define STA(buf, ks, sc) do { \
    char* d = &lds[buf][(ks) * ASLAB] + wid * 1024; \
    gl16(gA0 + (sc) + (ks) * 32, (u16*)d); \
    if constexpr (WM == 128) gl16(gA1 + (sc) + (ks) * 32, (u16*)(d + 8192)); \
  } while (0)
#define STB(buf, ks, sc) do { \
    char* d = &lds[buf][2 * ASLAB + (ks) * BSLAB] + wid * 1024; \
    gl16(gB0 + (sc) + (ks) * 32, (u16*)d); \
    gl16(gB1 + (sc) + (ks) * 32, (u16*)(d + 8192)); \
  } while (0)

#define GROUP(q, S1, S2, S3, S4) { \
    const char* bp = &lds[q][0]; \
    rdA(aF, bp, 0); rdB(bLo, bp, 0); S1; PBAR(); LG0(); \
    mf(aF, bLo, 0, 0);   PBAR(); \
    rdB(bHi, bp, 2);                S2; PBAR(); LG0(); \
    mf(aF, bHi, 0, 2);   PBAR(); \
    rdA(aF, bp, MIH);               S3; PBAR(); LG0(); \
    mf(aF, bHi, MIH, 2); PBAR(); \
    S4; VM4(); PBAR(); \
    mf(aF, bLo, MIH, 0); PBAR(); \
}

    STA(0, 0, 0); STA(0, 1, 0); STB(0, 0, 0); STB(0, 1, 0);
    STB(1, 0, 64); STB(1, 1, 64);
    VM4(); PBAR();

    const int nk = K >> 6;
    for (int T = 0; T < nk; T += 2) {
        const int c1 = (T + 1) << 6;
        const int c2 = (T + 2 < nk ? T + 2 : nk - 1) << 6;
        const int c3 = (T + 3 < nk ? T + 3 : nk - 1) << 6;
        GROUP(0, STA(1, 0, c1), STA(1, 1, c1), STB(0, 0, c2), STB(0, 1, c2))
        GROUP(1, STA(0, 0, c2), STA(0, 1, c2), STB(1, 0, c3), STB(1, 1, c3))
    }
    asm volatile("s_waitcnt vmcnt(0)" ::: "memory");

#undef GROUP
#undef STB
#undef STA

    const int crow0 = bm + wr * WM + kc * 4;
    const int ccol0 = bn + wc * 64 + fr;
    const size_t coff = (size_t)blockIdx.z * sC;

    float* C = (float*)Cv;
#pragma unroll
    for (int mi = 0; mi < 2 * MIH; mi++)
#pragma unroll
        for (int ni = 0; ni < 4; ni++)
#pragma unroll
            for (int r = 0; r < 4; r++) {
                float v = acc[mi][ni][r];
                if (EPI == 1) v *= scale;
                C[coff + (size_t)(crow0 + mi * 16 + r) * ldc + (ccol0 + ni * 16)] = v;
            }
}

// ---------------------------------------------------------------- softmax
// one block per row; 2048 fp32 scores (already scaled) -> 2048 bf16 probs
__global__ __launch_bounds__(256) void softmax_kernel(
        const float* __restrict__ S, u16* __restrict__ P) {
    __shared__ float redm[4];
    __shared__ float reds[4];
    const size_t base = (size_t)blockIdx.x * SEQ;
    const int t = threadIdx.x, lane = t & 63, wid = t >> 6;
    const float4* src = (const float4*)(S + base);
    float4 a = src[t], b = src[t + 256];

    float m = fmaxf(fmaxf(fmaxf(a.x, a.y), fmaxf(a.z, a.w)),
                    fmaxf(fmaxf(b.x, b.y), fmaxf(b.z, b.w)));
#pragma unroll
    for (int off = 32; off; off >>= 1) m = fmaxf(m, __shfl_xor(m, off, 64));
    if (lane == 0) redm[wid] = m;
    __syncthreads();
    m = fmaxf(fmaxf(redm[0], redm[1]), fmaxf(redm[2], redm[3]));

    float e[8];
    e[0] = __expf(a.x - m); e[1] = __expf(a.y - m);
    e[2] = __expf(a.z - m); e[3] = __expf(a.w - m);
    e[4] = __expf(b.x - m); e[5] = __expf(b.y - m);
    e[6] = __expf(b.z - m); e[7] = __expf(b.w - m);
    float s = e[0] + e[1] + e[2] + e[3] + e[4] + e[5] + e[6] + e[7];
#pragma unroll
    for (int off = 32; off; off >>= 1) s += __shfl_xor(s, off, 64);
    if (lane == 0) reds[wid] = s;
    __syncthreads();
    s = reds[0] + reds[1] + reds[2] + reds[3];
    const float r = 1.f / s;

    ushort4* dst = (ushort4*)(P + base);
    ushort4 o0, o1;
    o0.x = f32_bf16_rne(e[0] * r); o0.y = f32_bf16_rne(e[1] * r);
    o0.z = f32_bf16_rne(e[2] * r); o0.w = f32_bf16_rne(e[3] * r);
    o1.x = f32_bf16_rne(e[4] * r); o1.y = f32_bf16_rne(e[5] * r);
    o1.z = f32_bf16_rne(e[6] * r); o1.w = f32_bf16_rne(e[7] * r);
    dst[t] = o0;
    dst[t + 256] = o1;
}

// ---------------------------------------------------------------- launch
extern "C" void kernel_launch(void* const* d_in, const int* in_sizes, int n_in,
                              void* d_out, int out_size, void* d_ws, size_t ws_size,
                              hipStream_t stream) {
    const float* x    = (const float*)d_in[0];   // [4,2048,1024]
    const float* W    = (const float*)d_in[1];   // [3072,1024]
    const float* bias = (const float*)d_in[2];   // [3072]
    float* out = (float*)d_out;                  // [4,2048,1024]

    // workspace layout (191 MB total)
    u16* Xb  = (u16*)d_ws;                                  // 8192x1024 bf16
    u16* Wb  = Xb + (size_t)TOKENS * HIDDEN;                // 3072x1024 bf16
    u16* qkv = Wb + (size_t)QKVD * HIDDEN;                  // 8192x3072 bf16
    float* scores = (float*)(qkv + (size_t)TOKENS * QKVD);  // 4x2048x2048 f32
    u16* P  = (u16*)(scores + (size_t)BATCH * SEQ * SEQ);   // 4x2048x2048 bf16
    u16* Vt = P + (size_t)BATCH * SEQ * SEQ;                // 4x1024x2048 bf16

    // 1) fp32 -> bf16 casts (both tensors, one launch)
    {
        const int n4a = TOKENS * HIDDEN / 4;
        const int n4b = QKVD * HIDDEN / 4;
        const int n4t = n4a + n4b;
        cvt2_bf16_kernel<<<(n4t + 255) / 256, 256, 0, stream>>>(x, W, Xb, Wb, n4a, n4t);
    }

    // 2) QKV projection + fused V transpose.  grid 12x64 = 768:
    //    x<8 -> qkv Q,K columns; x>=8 -> Vt directly.
    gemm_qkv<<<dim3(QKVD / 256, TOKENS / 128, 1), 512, 0, stream>>>(
        Xb, Wb, qkv, Vt, bias);

    // 3) scores = scale * Q @ K^T per batch (f32 out)  grid 8x8x4 = 256
    gemm_bt<1, 128><<<dim3(SEQ / 256, SEQ / 256, BATCH), 512, 0, stream>>>(
        qkv, qkv + HIDDEN, scores, nullptr, HIDDEN, QKVD, QKVD, SEQ,
        (size_t)SEQ * QKVD, (size_t)SEQ * QKVD, (size_t)SEQ * SEQ, 0.03125f);

    // 4) row softmax -> bf16 P
    softmax_kernel<<<BATCH * SEQ, 256, 0, stream>>>(scores, P);

    // 5) out = P @ Vt^T per batch (f32 out)  WM=64: grid 4x16x4 = 256
    gemm_bt<2, 64><<<dim3(HIDDEN / 256, SEQ / 128, BATCH), 512, 0, stream>>>(
        P, Vt, out, nullptr, SEQ, SEQ, SEQ, HIDDEN,
        (size_t)SEQ * SEQ, (size_t)HIDDEN * SEQ, (size_t)SEQ * HIDDEN, 1.f);
}

// Round 6
// 253.045 us; speedup vs baseline: 1.0644x; 1.0248x over previous
//
#include <hip/hip_runtime.h>
#include <stdint.h>

#define HIDDEN 1024
#define BATCH  4
#define SEQ    2048
#define TOKENS (BATCH * SEQ)      // 8192
#define QKVD   (3 * HIDDEN)       // 3072

typedef unsigned short u16;
typedef __attribute__((ext_vector_type(8))) short   short8;   // 8 bf16 = 4 VGPRs
typedef __attribute__((ext_vector_type(4))) float   floatx4;

// deterministic round-to-nearest-even f32 -> bf16 (no NaN inputs here)
__device__ __forceinline__ u16 f32_bf16_rne(float f) {
    unsigned int u = __float_as_uint(f);
    u += 0x7FFFu + ((u >> 16) & 1u);
    return (u16)(u >> 16);
}

// async global->LDS, 16B per lane. LDS dest is wave-uniform base + lane*16.
__device__ __forceinline__ void gl16(const u16* g, u16* l) {
    __builtin_amdgcn_global_load_lds(
        (const __attribute__((address_space(1))) void*)g,
        (__attribute__((address_space(3))) void*)l, 16, 0, 0);
}

// ---- sync macros (two flavors, each verbatim from its measured-best round)
// R1 4-phase: wait until only the newest 3 staging loads remain in flight.
#define SYNC3() do { __builtin_amdgcn_sched_barrier(0); \
    asm volatile("s_waitcnt vmcnt(3)\n\ts_barrier" ::: "memory"); } while (0)
// R3 8-phase: raw barrier / lgkm drain / counted vmcnt(4)
#define PBAR() do { __builtin_amdgcn_sched_barrier(0); \
    asm volatile("s_barrier" ::: "memory"); } while (0)
#define LG0() asm volatile("s_waitcnt lgkmcnt(0)" ::: "memory")
#define VM4() do { __builtin_amdgcn_sched_barrier(0); \
    asm volatile("s_waitcnt vmcnt(4)" ::: "memory"); } while (0)

// ---------------------------------------------------------------- convert
__global__ __launch_bounds__(256) void cvt2_bf16_kernel(
        const float* __restrict__ sa, const float* __restrict__ sb,
        u16* __restrict__ da, u16* __restrict__ db, int n4a, int n4tot) {
    int i = blockIdx.x * 256 + threadIdx.x;
    if (i >= n4tot) return;
    float4 v;
    if (i < n4a) v = ((const float4*)sa)[i];
    else         v = ((const float4*)sb)[i - n4a];
    ushort4 o;
    o.x = f32_bf16_rne(v.x); o.y = f32_bf16_rne(v.y);
    o.z = f32_bf16_rne(v.z); o.w = f32_bf16_rne(v.w);
    if (i < n4a) ((ushort4*)da)[i] = o;
    else         ((ushort4*)db)[i - n4a] = o;
}

// ---------------------------------------------------------------- QKV GEMM
// qkv = Xb @ Wb^T + bias.  Round-1 4-phase kernel VERBATIM (measured best
// QKV across 6 variants: 65.0 us; the R5 fused-epilogue variant regressed to
// 72.9 us with 262K bank conflicts -> reverted to the plain epilogue).
// BM=128, BN=256, BK=64, 512 threads = 8 waves (2M x 4N), per-wave 64x64.
// Slab layout + XOR swizzle + vmcnt(3) pipeline verbatim (0 conflicts).
__global__ __launch_bounds__(512, 2) void gemm_qkv(
        const u16* __restrict__ A, const u16* __restrict__ B,
        u16* __restrict__ C, const float* __restrict__ bias) {
    __shared__ __align__(16) u16 lds[2][2][(128 + 256) * 32];   // 96 KB

    const int t    = threadIdx.x;
    const int lane = t & 63;
    const int wid  = t >> 6;
    const int wr   = wid >> 2;           // 0..1
    const int wc   = wid & 3;            // 0..3
    const int bm   = blockIdx.y * 128;
    const int bn   = blockIdx.x * 256;

    // staging source: thread t -> row t>>2, phys slot t&3,
    // global slot = (t&3) ^ ((row>>1)&3)
    const int rA  = t >> 2;
    const int sl  = (t & 3) ^ ((rA >> 1) & 3);
    const u16* gA  = A + (size_t)(bm + rA) * 1024 + sl * 8;
    const u16* gB0 = B + (size_t)(bn + rA) * 1024 + sl * 8;
    const u16* gB1 = gB0 + (size_t)128 * 1024;

    // fragment read geometry (verified 16x16x32 mappings)
    const int fr = lane & 15;
    const int kc = lane >> 4;
    const int fo = ((kc ^ ((fr >> 1) & 3)) << 4);
    const int aoffB = (wr * 64 + fr) * 64 + fo;
    const int boffB = (wc * 64 + fr) * 64 + fo;

    floatx4 acc[4][4];
#pragma unroll
    for (int i = 0; i < 4; i++)
#pragma unroll
        for (int j = 0; j < 4; j++) acc[i][j] = (floatx4){0.f, 0.f, 0.f, 0.f};

    short8 bfr0, bfr1, bfr2, bfr3, va0, va1;

#define LDB4(BASE) \
    bfr0 = *(const short8*)((BASE) + boffB);        \
    bfr1 = *(const short8*)((BASE) + boffB + 1024); \
    bfr2 = *(const short8*)((BASE) + boffB + 2048); \
    bfr3 = *(const short8*)((BASE) + boffB + 3072);

#define MFMA2(MI, A0, A1) \
    __builtin_amdgcn_s_setprio(1); \
    acc[MI][0]     = __builtin_amdgcn_mfma_f32_16x16x32_bf16(A0, bfr0, acc[MI][0], 0, 0, 0); \
    acc[MI][1]     = __builtin_amdgcn_mfma_f32_16x16x32_bf16(A0, bfr1, acc[MI][1], 0, 0, 0); \
    acc[MI][2]     = __builtin_amdgcn_mfma_f32_16x16x32_bf16(A0, bfr2, acc[MI][2], 0, 0, 0); \
    acc[MI][3]     = __builtin_amdgcn_mfma_f32_16x16x32_bf16(A0, bfr3, acc[MI][3], 0, 0, 0); \
    acc[(MI)+1][0] = __builtin_amdgcn_mfma_f32_16x16x32_bf16(A1, bfr0, acc[(MI)+1][0], 0, 0, 0); \
    acc[(MI)+1][1] = __builtin_amdgcn_mfma_f32_16x16x32_bf16(A1, bfr1, acc[(MI)+1][1], 0, 0, 0); \
    acc[(MI)+1][2] = __builtin_amdgcn_mfma_f32_16x16x32_bf16(A1, bfr2, acc[(MI)+1][2], 0, 0, 0); \
    acc[(MI)+1][3] = __builtin_amdgcn_mfma_f32_16x16x32_bf16(A1, bfr3, acc[(MI)+1][3], 0, 0, 0); \
    __builtin_amdgcn_s_setprio(0);

#define ITER(BUF, SBUF, SCOL) { \
    const char* As0_ = (const char*)&lds[BUF][0][0]; \
    const char* Bs0_ = As0_ + 8192; \
    const char* As1_ = (const char*)&lds[BUF][1][0]; \
    const char* Bs1_ = As1_ + 8192; \
    gl16(gA + (SCOL),       (u16*)((char*)&lds[SBUF][0][0]    + wid * 1024)); \
    LDB4(Bs0_); \
    va0 = *(const short8*)(As0_ + aoffB); \
    va1 = *(const short8*)(As0_ + aoffB + 1024); \
    MFMA2(0, va0, va1); \
    gl16(gB0 + (SCOL),      (u16*)((char*)&lds[SBUF][0][4096] + wid * 1024)); \
    gl16(gB1 + (SCOL),      (u16*)((char*)&lds[SBUF][0][8192] + wid * 1024)); \
    va0 = *(const short8*)(As0_ + aoffB + 2048); \
    va1 = *(const short8*)(As0_ + aoffB + 3072); \
    MFMA2(2, va0, va1); \
    SYNC3(); \
    gl16(gA + (SCOL) + 32,  (u16*)((char*)&lds[SBUF][1][0]    + wid * 1024)); \
    LDB4(Bs1_); \
    va0 = *(const short8*)(As1_ + aoffB); \
    va1 = *(const short8*)(As1_ + aoffB + 1024); \
    MFMA2(0, va0, va1); \
    gl16(gB0 + (SCOL) + 32, (u16*)((char*)&lds[SBUF][1][4096] + wid * 1024)); \
    gl16(gB1 + (SCOL) + 32, (u16*)((char*)&lds[SBUF][1][8192] + wid * 1024)); \
    va0 = *(const short8*)(As1_ + aoffB + 2048); \
    va1 = *(const short8*)(As1_ + aoffB + 3072); \
    MFMA2(2, va0, va1); \
    SYNC3(); }

    // prologue: tile 0 -> buf0 (ks0 set, ks1 set); vmcnt(3) drains the ks0
    // set, leaves the ks1 set in flight (= steady state).
    gl16(gA,       (u16*)((char*)&lds[0][0][0]    + wid * 1024));
    gl16(gB0,      (u16*)((char*)&lds[0][0][4096] + wid * 1024));
    gl16(gB1,      (u16*)((char*)&lds[0][0][8192] + wid * 1024));
    gl16(gA + 32,  (u16*)((char*)&lds[0][1][0]    + wid * 1024));
    gl16(gB0 + 32, (u16*)((char*)&lds[0][1][4096] + wid * 1024));
    gl16(gB1 + 32, (u16*)((char*)&lds[0][1][8192] + wid * 1024));
    SYNC3();

    const int nk = 1024 >> 6;            // 16 K-tiles
    for (int kt = 0; kt < nk; kt += 2) {
        const int c1 = (kt + 1) << 6;
        const int c2 = (kt + 2 < nk ? (kt + 2) : (nk - 1)) << 6;
        ITER(0, 1, c1)
        ITER(1, 0, c2)
    }
    asm volatile("s_waitcnt vmcnt(0)" ::: "memory");

#undef ITER
#undef MFMA2
#undef LDB4

    // epilogue: C/D 16x16 mapping col=lane&15, row=(lane>>4)*4+reg
    const int crow0 = bm + wr * 64 + kc * 4;
    const int ccol0 = bn + wc * 64 + fr;
    float bv[4];
#pragma unroll
    for (int ni = 0; ni < 4; ni++) bv[ni] = bias[ccol0 + ni * 16];
#pragma unroll
    for (int mi = 0; mi < 4; mi++)
#pragma unroll
        for (int ni = 0; ni < 4; ni++)
#pragma unroll
            for (int r = 0; r < 4; r++)
                C[(size_t)(crow0 + mi * 16 + r) * QKVD + (ccol0 + ni * 16)] =
                    f32_bf16_rne(acc[mi][ni][r] + bv[ni]);
}

// ---------------------------------------------------------------- GEMM (NT)
// Round-3 8-phase template, verbatim (measured best for scores+PV: the pair
// ran 14.2 us faster than the 4-phase pair; re-confirmed at R3 speed in R5).
// C[M,N] = A[M,K]*B[N,K]^T.  BM=2*WM, BN=256, BK=64, 512 threads, 8 waves.
// EPI: 1 = f32 store * scale; 2 = f32 store.
template <int EPI, int WM>
__global__ __launch_bounds__(512, 2) void gemm_bt(
        const u16* __restrict__ A, const u16* __restrict__ B,
        void* __restrict__ Cv, const float* __restrict__ bias,
        int K, int lda, int ldb, int ldc,
        size_t sA, size_t sB, size_t sC, float scale) {
    constexpr int BM    = 2 * WM;
    constexpr int MIH   = WM / 32;
    constexpr int ASLAB = BM * 64;
    constexpr int BSLAB = 256 * 64;
    constexpr int BUFB  = 2 * ASLAB + 2 * BSLAB;
    __shared__ __align__(16) char lds[2][BUFB];

    const int t    = threadIdx.x;
    const int lane = t & 63;
    const int wid  = t >> 6;
    const int wr   = wid >> 2;
    const int wc   = wid & 3;
    const int bm   = blockIdx.y * BM;
    const int bn   = blockIdx.x * 256;

    const u16* Ab = A + (size_t)blockIdx.z * sA;
    const u16* Bb = B + (size_t)blockIdx.z * sB;

    const int r0 = t >> 2;
    const int sl = (t & 3) ^ ((r0 >> 1) & 3);
    const u16* gA0 = Ab + (size_t)(bm + r0) * lda + sl * 8;
    const u16* gA1 = gA0 + (size_t)128 * lda;
    const u16* gB0 = Bb + (size_t)(bn + r0) * ldb + sl * 8;
    const u16* gB1 = gB0 + (size_t)128 * ldb;

    const int fr  = lane & 15;
    const int kc  = lane >> 4;
    const int frb = fr * 64 + ((kc ^ ((fr >> 1) & 3)) << 4);

    floatx4 acc[2 * MIH][4];
#pragma unroll
    for (int i = 0; i < 2 * MIH; i++)
#pragma unroll
        for (int j = 0; j < 4; j++) acc[i][j] = (floatx4){0.f, 0.f, 0.f, 0.f};

    short8 aF[MIH][2], bLo[2][2], bHi[2][2];

    auto rdA = [&](short8 (&dst)[MIH][2], const char* bp, int miBase) {
#pragma unroll
        for (int m = 0; m < MIH; m++)
#pragma unroll
            for (int ks = 0; ks < 2; ks++)
                dst[m][ks] = *(const short8*)(bp + ks * ASLAB +
                    (wr * WM + (miBase + m) * 16) * 64 + frb);
    };
    auto rdB = [&](short8 (&dst)[2][2], const char* bp, int niBase) {
#pragma unroll
        for (int n = 0; n < 2; n++)
#pragma unroll
            for (int ks = 0; ks < 2; ks++)
                dst[n][ks] = *(const short8*)(bp + 2 * ASLAB + ks * BSLAB +
                    (wc * 64 + (niBase + n) * 16) * 64 + frb);
    };
    auto mf = [&](short8 (&av)[MIH][2], short8 (&bv)[2][2], int miB, int niB) {
        __builtin_amdgcn_s_setprio(1);
#pragma unroll
        for (int m = 0; m < MIH; m++)
#pragma unroll
            for (int n = 0; n < 2; n++)
#pragma unroll
                for (int ks = 0; ks < 2; ks++)
                    acc[miB + m][niB + n] = __builtin_amdgcn_mfma_f32_16x16x32_bf16(
                        av[m][ks], bv[n][ks], acc[miB + m][niB + n], 0, 0, 0);
        __builtin_amdgcn_s_setprio(0);
    };

#define STA(buf, ks, sc) do { \
    char* d = &lds[buf][(ks) * ASLAB] + wid * 1024; \
    gl16(gA0 + (sc) + (ks) * 32, (u16*)d); \
    if constexpr (WM == 128) gl16(gA1 + (sc) + (ks) * 32, (u16*)(d + 8192)); \
  } while (0)
#define STB(buf, ks, sc) do { \
    char* d = &lds[buf][2 * ASLAB + (ks) * BSLAB] + wid * 1024; \
    gl16(gB0 + (sc) + (ks) * 32, (u16*)d); \
    gl16(gB1 + (sc) + (ks) * 32, (u16*)(d + 8192)); \
  } while (0)

#define GROUP(q, S1, S2, S3, S4) { \
    const char* bp = &lds[q][0]; \
    rdA(aF, bp, 0); rdB(bLo, bp, 0); S1; PBAR(); LG0(); \
    mf(aF, bLo, 0, 0);   PBAR(); \
    rdB(bHi, bp, 2);                S2; PBAR(); LG0(); \
    mf(aF, bHi, 0, 2);   PBAR(); \
    rdA(aF, bp, MIH);               S3; PBAR(); LG0(); \
    mf(aF, bHi, MIH, 2); PBAR(); \
    S4; VM4(); PBAR(); \
    mf(aF, bLo, MIH, 0); PBAR(); \
}

    STA(0, 0, 0); STA(0, 1, 0); STB(0, 0, 0); STB(0, 1, 0);
    STB(1, 0, 64); STB(1, 1, 64);
    VM4(); PBAR();

    const int nk = K >> 6;
    for (int T = 0; T < nk; T += 2) {
        const int c1 = (T + 1) << 6;
        const int c2 = (T + 2 < nk ? T + 2 : nk - 1) << 6;
        const int c3 = (T + 3 < nk ? T + 3 : nk - 1) << 6;
        GROUP(0, STA(1, 0, c1), STA(1, 1, c1), STB(0, 0, c2), STB(0, 1, c2))
        GROUP(1, STA(0, 0, c2), STA(0, 1, c2), STB(1, 0, c3), STB(1, 1, c3))
    }
    asm volatile("s_waitcnt vmcnt(0)" ::: "memory");

#undef GROUP
#undef STB
#undef STA

    const int crow0 = bm + wr * WM + kc * 4;
    const int ccol0 = bn + wc * 64 + fr;
    const size_t coff = (size_t)blockIdx.z * sC;

    float* C = (float*)Cv;
#pragma unroll
    for (int mi = 0; mi < 2 * MIH; mi++)
#pragma unroll
        for (int ni = 0; ni < 4; ni++)
#pragma unroll
            for (int r = 0; r < 4; r++) {
                float v = acc[mi][ni][r];
                if (EPI == 1) v *= scale;
                C[coff + (size_t)(crow0 + mi * 16 + r) * ldc + (ccol0 + ni * 16)] = v;
            }
}

// ------------------------------------------------- softmax + V transpose
// One launch, blockIdx split (saves a dispatch gap; both memory-bound and
// independent, so their blocks overlap across CUs):
//   blockIdx.x < TOKENS : row softmax, 2048 f32 scores -> 2048 bf16 probs
//   blockIdx.x >= TOKENS: 64x64 V-transpose tile, qkv V-cols -> Vt
__global__ __launch_bounds__(256) void softmax_tr_kernel(
        const float* __restrict__ S, u16* __restrict__ P,
        const u16* __restrict__ qkv, u16* __restrict__ Vt) {
    __shared__ float redm[4];
    __shared__ float reds[4];
    __shared__ u16 tile[64][66];
    const int t = threadIdx.x;

    if ((int)blockIdx.x < TOKENS) {
        const size_t base = (size_t)blockIdx.x * SEQ;
        const int lane = t & 63, wid = t >> 6;
        const float4* src = (const float4*)(S + base);
        float4 a = src[t], b = src[t + 256];

        float m = fmaxf(fmaxf(fmaxf(a.x, a.y), fmaxf(a.z, a.w)),
                        fmaxf(fmaxf(b.x, b.y), fmaxf(b.z, b.w)));
#pragma unroll
        for (int off = 32; off; off >>= 1) m = fmaxf(m, __shfl_xor(m, off, 64));
        if (lane == 0) redm[wid] = m;
        __syncthreads();
        m = fmaxf(fmaxf(redm[0], redm[1]), fmaxf(redm[2], redm[3]));

        float e[8];
        e[0] = __expf(a.x - m); e[1] = __expf(a.y - m);
        e[2] = __expf(a.z - m); e[3] = __expf(a.w - m);
        e[4] = __expf(b.x - m); e[5] = __expf(b.y - m);
        e[6] = __expf(b.z - m); e[7] = __expf(b.w - m);
        float s = e[0] + e[1] + e[2] + e[3] + e[4] + e[5] + e[6] + e[7];
#pragma unroll
        for (int off = 32; off; off >>= 1) s += __shfl_xor(s, off, 64);
        if (lane == 0) reds[wid] = s;
        __syncthreads();
        s = reds[0] + reds[1] + reds[2] + reds[3];
        const float r = 1.f / s;

        ushort4* dst = (ushort4*)(P + base);
        ushort4 o0, o1;
        o0.x = f32_bf16_rne(e[0] * r); o0.y = f32_bf16_rne(e[1] * r);
        o0.z = f32_bf16_rne(e[2] * r); o0.w = f32_bf16_rne(e[3] * r);
        o1.x = f32_bf16_rne(e[4] * r); o1.y = f32_bf16_rne(e[5] * r);
        o1.z = f32_bf16_rne(e[6] * r); o1.w = f32_bf16_rne(e[7] * r);
        dst[t] = o0;
        dst[t + 256] = o1;
    } else {
        // transposeV (verbatim R1-R4 kernel, grid flattened):
        // Vt[b][h][s] <- qkv[b*SEQ+s][2*HIDDEN+h], 64x64 tiles, pad 66
        const int bx = blockIdx.x - TOKENS;       // 0..2047
        const int b  = bx >> 9;                   // 32*16 tiles per batch
        const int s0 = (bx & 31) * 64;
        const int h0 = ((bx >> 5) & 15) * 64;
        const int c = t & 63, r4 = t >> 6;
#pragma unroll
        for (int i = 0; i < 16; i++) {
            int sl = i * 4 + r4;
            tile[sl][c] = qkv[(size_t)(b * SEQ + s0 + sl) * QKVD + 2 * HIDDEN + h0 + c];
        }
        __syncthreads();
#pragma unroll
        for (int i = 0; i < 16; i++) {
            int hl = i * 4 + r4;
            Vt[(size_t)(b * HIDDEN + h0 + hl) * SEQ + s0 + c] = tile[c][hl];
        }
    }
}

// ---------------------------------------------------------------- launch
extern "C" void kernel_launch(void* const* d_in, const int* in_sizes, int n_in,
                              void* d_out, int out_size, void* d_ws, size_t ws_size,
                              hipStream_t stream) {
    const float* x    = (const float*)d_in[0];   // [4,2048,1024]
    const float* W    = (const float*)d_in[1];   // [3072,1024]
    const float* bias = (const float*)d_in[2];   // [3072]
    float* out = (float*)d_out;                  // [4,2048,1024]

    // workspace layout (191 MB total)
    u16* Xb  = (u16*)d_ws;                                  // 8192x1024 bf16
    u16* Wb  = Xb + (size_t)TOKENS * HIDDEN;                // 3072x1024 bf16
    u16* qkv = Wb + (size_t)QKVD * HIDDEN;                  // 8192x3072 bf16
    float* scores = (float*)(qkv + (size_t)TOKENS * QKVD);  // 4x2048x2048 f32
    u16* P  = (u16*)(scores + (size_t)BATCH * SEQ * SEQ);   // 4x2048x2048 bf16
    u16* Vt = P + (size_t)BATCH * SEQ * SEQ;                // 4x1024x2048 bf16

    // 1) fp32 -> bf16 casts (both tensors, one launch)
    {
        const int n4a = TOKENS * HIDDEN / 4;
        const int n4b = QKVD * HIDDEN / 4;
        const int n4t = n4a + n4b;
        cvt2_bf16_kernel<<<(n4t + 255) / 256, 256, 0, stream>>>(x, W, Xb, Wb, n4a, n4t);
    }

    // 2) QKV projection (R1 4-phase, measured best).  grid 12x64 = 768
    gemm_qkv<<<dim3(QKVD / 256, TOKENS / 128, 1), 512, 0, stream>>>(
        Xb, Wb, qkv, bias);

    // 3) scores = scale * Q @ K^T per batch (R3 8-phase WM=128)  grid 8x8x4
    gemm_bt<1, 128><<<dim3(SEQ / 256, SEQ / 256, BATCH), 512, 0, stream>>>(
        qkv, qkv + HIDDEN, scores, nullptr, HIDDEN, QKVD, QKVD, SEQ,
        (size_t)SEQ * QKVD, (size_t)SEQ * QKVD, (size_t)SEQ * SEQ, 0.03125f);

    // 4) row softmax + V transpose in one launch (8192 + 2048 blocks)
    softmax_tr_kernel<<<TOKENS + 2048, 256, 0, stream>>>(scores, P, qkv, Vt);

    // 5) out = P @ Vt^T per batch (R3 8-phase WM=64)  grid 4x16x4 = 256
    gemm_bt<2, 64><<<dim3(HIDDEN / 256, SEQ / 128, BATCH), 512, 0, stream>>>(
        P, Vt, out, nullptr, SEQ, SEQ, SEQ, HIDDEN,
        (size_t)SEQ * SEQ, (size_t)HIDDEN * SEQ, (size_t)SEQ * HIDDEN, 1.f);
}